// Round 3
// baseline (441.883 us; speedup 1.0000x reference)
//
#include <hip/hip_runtime.h>
#include <hip/hip_bf16.h>
#include <math.h>
#include <stdint.h>

// ArcFace loss via MX-fp8 (e4m3, identity scales) MFMA GEMM + fused
// fixed-max softmax. B=2048, D=512, C=50000. Output: scalar mean NLL (f32).
//
// R8: single fix over R7 -- __launch_bounds__(512, 2) was interpreted as
//     2 blocks/CU (CUDA minBlocks semantics): 16 waves/CU = 4 waves/SIMD ->
//     VGPR cap 512/4 = 128 -> accumulator spilled to scratch (WRITE_SIZE
//     432 MB/dispatch, k_gemm 275us). Now (512, 1): cap >= 256 VGPR, no
//     spill. Structure otherwise identical: 256x256 tile, 8 waves, BK=128,
//     double-buffered LDS, one barrier per K-step, stage-before-compute.
//
// Numerics: logits = 30*cos in [-30,30] -> fixed max 30, plain sums:
//   lse = 30 + log(sum_c exp(l_c - 30)); label logit recomputed exactly in
//   fp32 at finalize, so fp8 error only perturbs the softmax denominator.

#define B_ROWS    2048
#define D_DIM     512
#define C_CLASSES 50000
#define C_PAD     50176            // 196 * 256
#define NCHUNK    196              // 256-wide chunks
#define ARC_MARGIN 0.3f
#define ARC_SCALE  30.0f
#define ARC_EPS    1e-12f
#define K_LOG2E_S  43.2808512f     // 30 * log2(e)

// workspace layout (bytes)
#define OFF_WQ    0u               // 50176*512 = 25,690,112
#define OFF_EMBQ  25690112u        // 2048*512  =  1,048,576
#define OFF_WINV  26738688u        // 50000*4   =    200,000
#define OFF_EINV  26938688u        // 2048*4    =      8,192
#define OFF_PART  26946880u        // 2048*196*4 = 1,605,632  -> total ~28.6 MB

typedef __attribute__((ext_vector_type(8))) int   i32x8;
typedef __attribute__((ext_vector_type(4))) int   i32x4;
typedef __attribute__((ext_vector_type(4))) float f32x4;

typedef __attribute__((address_space(1))) const unsigned int g_u32;
typedef __attribute__((address_space(3))) unsigned int       l_u32;

__device__ __forceinline__ void gload_lds16(const void* g, void* l) {
    // dest is wave-uniform LDS base; HW writes lane i at base + i*16
    g_u32* gp = (g_u32*)(uintptr_t)g;
    l_u32* lp = (l_u32*)(uintptr_t)l;
    __builtin_amdgcn_global_load_lds(gp, lp, 16, 0, 0);
}

// ---------------- prep: rows -> normalized e4m3 + inverse norms ----------------
// One wave per 4 consecutive rows. Row space: [0,C_PAD) = weight (pad rows
// zero-filled), [C_PAD, C_PAD+B) = embeddings. All segments are multiples of
// 4 rows (50000, 176, 2048), so a 4-row group never straddles segments.
__global__ __launch_bounds__(256) void k_prep(const float* __restrict__ emb,
                                              const float* __restrict__ weight,
                                              uint8_t* __restrict__ embq,
                                              uint8_t* __restrict__ wq,
                                              float* __restrict__ einv,
                                              float* __restrict__ winv,
                                              float* __restrict__ out) {
    if (blockIdx.x == 0 && threadIdx.x == 0) out[0] = 0.f;  // zero for k_fin atomics
    int wave = blockIdx.x * (blockDim.x >> 6) + (threadIdx.x >> 6);
    int lane = threadIdx.x & 63;
    int g0   = wave << 2;              // first of 4 consecutive rows

    const float* src;
    uint8_t* dst;
    float* invout;
    if (g0 >= C_PAD) {                 // embedding rows
        int row = g0 - C_PAD;
        src = emb + (size_t)row * D_DIM;
        dst = embq + (size_t)row * D_DIM;
        invout = einv + row;
    } else if (g0 >= C_CLASSES) {      // zero-fill pad classes
        int2 z = make_int2(0, 0);
        #pragma unroll
        for (int r = 0; r < 4; ++r)
            *(int2*)(wq + (size_t)(g0 + r) * D_DIM + lane * 8) = z;
        return;
    } else {                           // weight rows
        src = weight + (size_t)g0 * D_DIM;
        dst = wq + (size_t)g0 * D_DIM;
        invout = winv + g0;
    }

    // issue all 8 loads before any use: 128 B/lane outstanding
    const float4* r4 = (const float4*)src;
    float4 v[8];
    #pragma unroll
    for (int r = 0; r < 4; ++r) {
        v[2 * r]     = r4[r * 128 + lane * 2];
        v[2 * r + 1] = r4[r * 128 + lane * 2 + 1];
    }

    #pragma unroll
    for (int r = 0; r < 4; ++r) {
        float4 v0 = v[2 * r], v1 = v[2 * r + 1];
        float s = v0.x*v0.x + v0.y*v0.y + v0.z*v0.z + v0.w*v0.w
                + v1.x*v1.x + v1.y*v1.y + v1.z*v1.z + v1.w*v1.w;
        #pragma unroll
        for (int off = 32; off; off >>= 1) s += __shfl_xor(s, off);
        float rn = 1.0f / fmaxf(sqrtf(s), ARC_EPS);
        if (lane == 0) invout[r] = rn;
        int p0 = __builtin_amdgcn_cvt_pk_fp8_f32(v0.x * rn, v0.y * rn, 0, false);
        p0     = __builtin_amdgcn_cvt_pk_fp8_f32(v0.z * rn, v0.w * rn, p0, true);
        int p1 = __builtin_amdgcn_cvt_pk_fp8_f32(v1.x * rn, v1.y * rn, 0, false);
        p1     = __builtin_amdgcn_cvt_pk_fp8_f32(v1.z * rn, v1.w * rn, p1, true);
        *(int2*)(dst + (size_t)r * D_DIM + lane * 8) = make_int2(p0, p1);
    }
}

struct TrueT  { static constexpr bool value = true;  };
struct FalseT { static constexpr bool value = false; };

// ---------------- GEMM (MX-fp8, identity scales) + softmax partials -----------
// 256x256 tile, 8 waves (2 N-halves x 4 M-quarters), wave tile 64x128.
// Double-buffered LDS: SMEM[buf] = [A 32KB | B 32KB]; one barrier per K-step.
// LDS cell layout per 16-row block: [kc 0..7][row 0..15] 16B cells -- lane
// order of global_load_lds matches, frag ds_read_b128 conflict-free (as R5/R6).
__global__ __launch_bounds__(512, 1) void k_gemm(const uint8_t* __restrict__ embq,
                                                 const uint8_t* __restrict__ wq,
                                                 float* __restrict__ partials) {
    __shared__ __align__(16) uint8_t SMEM[2][65536];   // 128 KiB total
    float (*Red)[2] = (float (*)[2])&SMEM[0][0];       // aliased after compute

    const int tid    = threadIdx.x;
    const int w      = tid >> 6;        // wave 0..7
    const int lane   = tid & 63;
    const int lanelo = lane & 15;
    const int quad   = lane >> 4;
    const int wr     = w >> 1;          // 0..3 : M quarter (64 rows)
    const int wc     = w & 1;           // 0..1 : N half (128 cols)

    // XCD-affinity decode: all 8 row-blocks of a chunk share id%8 -> same XCD
    // (round-robin dispatch heuristic). Per-XCD B slice ~3.2MB fits 4MB L2.
    const int id    = blockIdx.x;
    const int xcd   = id & 7;
    const int slot  = id >> 3;          // 0..199
    const int rb_   = slot & 7;         // row-block 0..7
    const int ci    = slot >> 3;        // 0..24
    const int chunk = xcd + (ci << 3);
    if (chunk >= NCHUNK) return;        // 32 pad blocks
    const int b0 = rb_ * 256;
    const int n0 = chunk * 256;

    const uint8_t* Abase = embq + (size_t)b0 * D_DIM;
    const uint8_t* Bbase = wq   + (size_t)n0 * D_DIM;

    f32x4 acc[4][8];
    #pragma unroll
    for (int i = 0; i < 4; ++i)
        #pragma unroll
        for (int j = 0; j < 8; ++j)
            acc[i][j] = (f32x4){0.f, 0.f, 0.f, 0.f};

    const int srow = lane & 15;
    const int skc  = lane >> 4;

    // stage one 256x128 A panel + 256x128 B panel (64 KB) into buffer bufsel;
    // 8 gload_lds16 per wave (4 A + 4 B), 8 waves cover rb 0..15 for each.
    auto stage = [&](int bufsel, int kt) {
        uint8_t* dstA = &SMEM[bufsel][0];
        uint8_t* dstB = &SMEM[bufsel][32768];
        const int k0 = kt * 128;
        #pragma unroll
        for (int t = 0; t < 2; ++t) {
            const int rb = w * 2 + t;                 // 0..15
            const size_t go = (size_t)(rb * 16 + srow) * D_DIM + k0;
            #pragma unroll
            for (int h = 0; h < 2; ++h) {
                const int kc = h * 4 + skc;           // 0..7
                gload_lds16(Abase + go + kc * 16, dstA + rb * 2048 + h * 1024);
                gload_lds16(Bbase + go + kc * 16, dstB + rb * 2048 + h * 1024);
            }
        }
    };

    stage(0, 0);
    __syncthreads();                    // prologue drain: buf0 resident

    #pragma unroll
    for (int kt = 0; kt < 4; ++kt) {
        const int buf = kt & 1;
        if (kt < 3) stage(buf ^ 1, kt + 1);   // issue next tile BEFORE compute

        const uint8_t* Abuf = &SMEM[buf][0];
        const uint8_t* Bbuf = &SMEM[buf][32768];

        i32x8 af[4];                    // wave's 64 A rows, this K-step
        #pragma unroll
        for (int i = 0; i < 4; ++i) {
            const int rb = wr * 4 + i;
            i32x4 lo = *(const i32x4*)&Abuf[rb * 2048 + quad * 512 + lanelo * 16];
            i32x4 hi = *(const i32x4*)&Abuf[rb * 2048 + quad * 512 + 256 + lanelo * 16];
            af[i] = (i32x8){lo[0], lo[1], lo[2], lo[3], hi[0], hi[1], hi[2], hi[3]};
        }
        #pragma unroll
        for (int j = 0; j < 8; ++j) {   // stream B frags: 32 MFMA burst
            const int rb = wc * 8 + j;
            i32x4 lo = *(const i32x4*)&Bbuf[rb * 2048 + quad * 512 + lanelo * 16];
            i32x4 hi = *(const i32x4*)&Bbuf[rb * 2048 + quad * 512 + 256 + lanelo * 16];
            i32x8 bf = (i32x8){lo[0], lo[1], lo[2], lo[3], hi[0], hi[1], hi[2], hi[3]};
            #pragma unroll
            for (int i = 0; i < 4; ++i)
                acc[i][j] = __builtin_amdgcn_mfma_scale_f32_16x16x128_f8f6f4(
                    af[i], bf, acc[i][j],
                    0, 0,          // cbsz=fp8(e4m3), blgp=fp8(e4m3)
                    0, 127,        // scale A: identity (E8M0 127 = 1.0)
                    0, 127);       // scale B: identity
        }
        __syncthreads();               // vmcnt(0)+lgkmcnt(0)+barrier: next tile
    }                                  // resident, this buffer reusable

    // epilogue: C/D layout col=lane&15, row=quad*4+reg (shape-determined).
    // Red aliases SMEM[0]: buf0's last reads completed before kt=2's barrier.
    auto epi = [&](auto maskTag) {
        constexpr bool MASK = decltype(maskTag)::value;
        #pragma unroll
        for (int i = 0; i < 4; ++i) {
            #pragma unroll
            for (int reg = 0; reg < 4; ++reg) {
                float s4 = 0.f;
                #pragma unroll
                for (int j = 0; j < 8; ++j) {
                    float t = __builtin_amdgcn_exp2f(
                        fmaf(acc[i][j][reg], K_LOG2E_S, -K_LOG2E_S));
                    if (MASK) {
                        int c = n0 + wc * 128 + j * 16 + lanelo;
                        if (c >= C_CLASSES) t = 0.f;
                    }
                    s4 += t;
                }
                #pragma unroll
                for (int off = 1; off < 16; off <<= 1)
                    s4 += __shfl_xor(s4, off);
                if (lanelo == 0)
                    Red[wr * 64 + i * 16 + quad * 4 + reg][wc] = s4;
            }
        }
    };
    if (chunk == NCHUNK - 1) epi(TrueT{}); else epi(FalseT{});
    __syncthreads();

    if (tid < 256)
        partials[(size_t)(b0 + tid) * NCHUNK + chunk] = Red[tid][0] + Red[tid][1];
}

// -------- finalize: exact label logit + partial sum -> atomic mean NLL --------
// 2 waves per row: role 0 = exact label dot, role 1 = partials sum.
__global__ __launch_bounds__(256) void k_fin(const float* __restrict__ emb,
                                             const float* __restrict__ weight,
                                             const float* __restrict__ einv,
                                             const float* __restrict__ winv,
                                             const int* __restrict__ labels,
                                             const float* __restrict__ partials,
                                             float* __restrict__ out) {
    __shared__ float s_dot[2], s_ls[2];
    int widx = threadIdx.x >> 6;       // 0..3
    int lane = threadIdx.x & 63;
    int rloc = widx & 1;               // row within block
    int role = widx >> 1;              // 0 = dot, 1 = partials
    int b    = blockIdx.x * 2 + rloc;

    if (role == 0) {
        int label = labels[b];
        const float4* e  = (const float4*)(emb + (size_t)b * D_DIM);
        const float4* wt = (const float4*)(weight + (size_t)label * D_DIM);
        float4 e0 = e[lane],  e1 = e[lane + 64];
        float4 w0 = wt[lane], w1 = wt[lane + 64];
        float dot = e0.x*w0.x + e0.y*w0.y + e0.z*w0.z + e0.w*w0.w
                  + e1.x*w1.x + e1.y*w1.y + e1.z*w1.z + e1.w*w1.w;
        #pragma unroll
        for (int off = 32; off; off >>= 1) dot += __shfl_xor(dot, off);
        if (lane == 0) s_dot[rloc] = dot;
    } else {
        float p[4];
        #pragma unroll
        for (int t = 0; t < 4; ++t) {
            int idx = lane + t * 64;
            p[t] = (idx < NCHUNK) ? partials[(size_t)b * NCHUNK + idx] : 0.f;
        }
        float ls = p[0];
        #pragma unroll
        for (int t = 1; t < 4; ++t) ls += p[t];
        #pragma unroll
        for (int off = 32; off; off >>= 1) ls += __shfl_xor(ls, off);
        if (lane == 0) s_ls[rloc] = ls;
    }
    __syncthreads();

    if (threadIdx.x < 2) {
        int r = threadIdx.x;
        int b2 = blockIdx.x * 2 + r;
        int label = labels[b2];
        float cosv   = s_dot[r] * einv[b2] * winv[label];
        float l_orig = ARC_SCALE * cosv;
        float l_adj  = ARC_SCALE * (cosv - ARC_MARGIN);
        // swap (fp8-accumulated) label term for exact margin-adjusted one
        float s_adj = s_ls[r] - __expf(l_orig - ARC_SCALE) + __expf(l_adj - ARC_SCALE);
        float v = ARC_SCALE + logf(s_adj) - l_adj;
        atomicAdd(out, v * (1.0f / (float)B_ROWS));
    }
}

extern "C" void kernel_launch(void* const* d_in, const int* in_sizes, int n_in,
                              void* d_out, int out_size, void* d_ws, size_t ws_size,
                              hipStream_t stream) {
    const float* emb    = (const float*)d_in[0];   // (2048, 512) f32
    const int*   labels = (const int*)d_in[1];     // (2048,)
    const float* weight = (const float*)d_in[2];   // (50000, 512) f32
    float* out = (float*)d_out;

    char* ws = (char*)d_ws;
    uint8_t* wq    = (uint8_t*)(ws + OFF_WQ);
    uint8_t* embq  = (uint8_t*)(ws + OFF_EMBQ);
    float* winv     = (float*)(ws + OFF_WINV);
    float* einv     = (float*)(ws + OFF_EINV);
    float* partials = (float*)(ws + OFF_PART);

    // (C_PAD + B_ROWS) rows, 4 rows/wave, 4 waves/block
    k_prep<<<(C_PAD + B_ROWS) / 16, 256, 0, stream>>>(emb, weight, embq, wq,
                                                      einv, winv, out);

    // 8 xcd slots x (8 row-blocks x 25 ci) = 1600 blocks (32 early-return)
    k_gemm<<<1600, 512, 0, stream>>>(embq, wq, partials);

    k_fin<<<B_ROWS / 2, 256, 0, stream>>>(emb, weight, einv, winv, labels,
                                          partials, out);
}

// Round 4
// 240.858 us; speedup vs baseline: 1.8346x; 1.8346x over previous
//
#include <hip/hip_runtime.h>
#include <hip/hip_bf16.h>
#include <math.h>
#include <stdint.h>

// ArcFace loss via MX-fp8 (e4m3, identity scales) MFMA GEMM + fused
// fixed-max softmax. B=2048, D=512, C=50000. Output: scalar mean NLL (f32).
//
// R9: k_gemm restructured -- "A-in-registers, fused exp-sum" (the 256x256
//     C-tile approach of R7/R8 is unfixable: 512-thread blocks are capped at
//     128 regs by the toolchain -> guaranteed spill). New structure:
//       * 4-wave/256-thr blocks (compiler uses AGPRs freely there: R5 proof).
//       * wave holds its 32 A-rows' ENTIRE K=512 in regs (8 x i32x8 = 64 VGPR,
//         loaded once per block; embq is L2-resident).
//       * N consumed in 32-col strips staged in LDS (2x16KB dbuf); per strip
//         per wave: 16 ds_read_b128 + 16 MFMA + fused exp2-accumulate into
//         rs[8] -- NO C-tile, NO separate epilogue pass, ONE barrier/strip.
//       * grid 16 rb x 112 chunks(448 cols) = 1792 = 8 XCD x 14: exact
//         XCD L2 affinity (3.2MB B slice per XCD reused by all 16 rbs).
//     prep/fin unchanged.
//
// Numerics: logits = 30*cos in [-30,30] -> fixed max 30, plain sums:
//   lse = 30 + log(sum_c exp(l_c - 30)); label logit recomputed exactly in
//   fp32 at finalize, so fp8 error only perturbs the softmax denominator.

#define B_ROWS    2048
#define D_DIM     512
#define C_CLASSES 50000
#define C_PAD     50176            // 112 * 448
#define NCHUNK    112              // 448-wide chunks
#define CH_COLS   448
#define NSTRIP    14               // 32-col strips per chunk
#define ARC_MARGIN 0.3f
#define ARC_SCALE  30.0f
#define ARC_EPS    1e-12f
#define K_LOG2E_S  43.2808512f     // 30 * log2(e)

// workspace layout (bytes)
#define OFF_WQ    0u               // 50176*512 = 25,690,112
#define OFF_EMBQ  25690112u        // 2048*512  =  1,048,576
#define OFF_WINV  26738688u        // 50000*4   =    200,000
#define OFF_EINV  26938688u        // 2048*4    =      8,192
#define OFF_PART  26946880u        // 2048*112*4 =   917,504  -> total ~27.9 MB

typedef __attribute__((ext_vector_type(8))) int   i32x8;
typedef __attribute__((ext_vector_type(4))) int   i32x4;
typedef __attribute__((ext_vector_type(4))) float f32x4;

typedef __attribute__((address_space(1))) const unsigned int g_u32;
typedef __attribute__((address_space(3))) unsigned int       l_u32;

__device__ __forceinline__ void gload_lds16(const void* g, void* l) {
    // dest is wave-uniform LDS base; HW writes lane i at base + i*16
    g_u32* gp = (g_u32*)(uintptr_t)g;
    l_u32* lp = (l_u32*)(uintptr_t)l;
    __builtin_amdgcn_global_load_lds(gp, lp, 16, 0, 0);
}

// ---------------- prep: rows -> normalized e4m3 + inverse norms ----------------
// One wave per 4 consecutive rows. Row space: [0,C_PAD) = weight (pad rows
// zero-filled), [C_PAD, C_PAD+B) = embeddings. All segments are multiples of
// 4 rows (50000, 176, 2048), so a 4-row group never straddles segments.
__global__ __launch_bounds__(256) void k_prep(const float* __restrict__ emb,
                                              const float* __restrict__ weight,
                                              uint8_t* __restrict__ embq,
                                              uint8_t* __restrict__ wq,
                                              float* __restrict__ einv,
                                              float* __restrict__ winv,
                                              float* __restrict__ out) {
    if (blockIdx.x == 0 && threadIdx.x == 0) out[0] = 0.f;  // zero for k_fin atomics
    int wave = blockIdx.x * (blockDim.x >> 6) + (threadIdx.x >> 6);
    int lane = threadIdx.x & 63;
    int g0   = wave << 2;              // first of 4 consecutive rows

    const float* src;
    uint8_t* dst;
    float* invout;
    if (g0 >= C_PAD) {                 // embedding rows
        int row = g0 - C_PAD;
        src = emb + (size_t)row * D_DIM;
        dst = embq + (size_t)row * D_DIM;
        invout = einv + row;
    } else if (g0 >= C_CLASSES) {      // zero-fill pad classes
        int2 z = make_int2(0, 0);
        #pragma unroll
        for (int r = 0; r < 4; ++r)
            *(int2*)(wq + (size_t)(g0 + r) * D_DIM + lane * 8) = z;
        return;
    } else {                           // weight rows
        src = weight + (size_t)g0 * D_DIM;
        dst = wq + (size_t)g0 * D_DIM;
        invout = winv + g0;
    }

    // issue all 8 loads before any use: 128 B/lane outstanding
    const float4* r4 = (const float4*)src;
    float4 v[8];
    #pragma unroll
    for (int r = 0; r < 4; ++r) {
        v[2 * r]     = r4[r * 128 + lane * 2];
        v[2 * r + 1] = r4[r * 128 + lane * 2 + 1];
    }

    #pragma unroll
    for (int r = 0; r < 4; ++r) {
        float4 v0 = v[2 * r], v1 = v[2 * r + 1];
        float s = v0.x*v0.x + v0.y*v0.y + v0.z*v0.z + v0.w*v0.w
                + v1.x*v1.x + v1.y*v1.y + v1.z*v1.z + v1.w*v1.w;
        #pragma unroll
        for (int off = 32; off; off >>= 1) s += __shfl_xor(s, off);
        float rn = 1.0f / fmaxf(sqrtf(s), ARC_EPS);
        if (lane == 0) invout[r] = rn;
        int p0 = __builtin_amdgcn_cvt_pk_fp8_f32(v0.x * rn, v0.y * rn, 0, false);
        p0     = __builtin_amdgcn_cvt_pk_fp8_f32(v0.z * rn, v0.w * rn, p0, true);
        int p1 = __builtin_amdgcn_cvt_pk_fp8_f32(v1.x * rn, v1.y * rn, 0, false);
        p1     = __builtin_amdgcn_cvt_pk_fp8_f32(v1.z * rn, v1.w * rn, p1, true);
        *(int2*)(dst + (size_t)r * D_DIM + lane * 8) = make_int2(p0, p1);
    }
}

struct TrueT  { static constexpr bool value = true;  };
struct FalseT { static constexpr bool value = false; };

// ---------------- GEMM (MX-fp8, identity scales) + fused exp-sum -------------
// Block: 4 waves x 32 rows = 128 rows; chunk = 448 cols = 14 strips of 32.
// Wave's A rows (32 x 512B) live in regs (afA/afB, 64 VGPR). B strips staged
// in LDS (2 x 16KB dbuf), cell layout per 16-col group: [kc 0..31][col 0..15]
// 16B cells (gload_lds lane order == layout; frag ds_read_b128 conflict-free,
// same pattern as R5 which measured 0 bank conflicts).
__global__ __launch_bounds__(256) void k_gemm(const uint8_t* __restrict__ embq,
                                              const uint8_t* __restrict__ wq,
                                              float* __restrict__ partials) {
    __shared__ __align__(16) uint8_t Bs[2][16384];

    const int tid  = threadIdx.x;
    const int w    = tid >> 6;         // wave 0..3
    const int lane = tid & 63;
    const int c    = lane & 15;        // row/col within 16-group
    const int q    = lane >> 4;        // k-slice quad

    // XCD-affinity: consecutive ids round-robin XCDs; XCD x owns chunks
    // [x*14, x*14+14) for ALL row-blocks -> 3.2MB B slice stays in its L2.
    const int id  = blockIdx.x;        // 0..1791
    const int xcd = id & 7;
    const int s   = id >> 3;           // 0..223
    const int ci  = s % 14;
    const int rb  = s / 14;            // 0..15
    const int chunk = xcd * 14 + ci;
    const int b0 = rb * 128;
    const int n0 = chunk * CH_COLS;

    // ---- A fragments: wave's 32 rows, full K=512, in registers ----
    const int r0 = b0 + w * 32;
    i32x8 afA[4], afB[4];
    #pragma unroll
    for (int kt = 0; kt < 4; ++kt) {
        const uint8_t* pa = embq + (size_t)(r0 + c) * D_DIM + kt * 128 + q * 32;
        const uint8_t* pb = embq + (size_t)(r0 + 16 + c) * D_DIM + kt * 128 + q * 32;
        i32x4 alo = *(const i32x4*)pa;
        i32x4 ahi = *(const i32x4*)(pa + 16);
        i32x4 blo = *(const i32x4*)pb;
        i32x4 bhi = *(const i32x4*)(pb + 16);
        afA[kt] = (i32x8){alo[0], alo[1], alo[2], alo[3], ahi[0], ahi[1], ahi[2], ahi[3]};
        afB[kt] = (i32x8){blo[0], blo[1], blo[2], blo[3], bhi[0], bhi[1], bhi[2], bhi[3]};
    }

    // ---- staging: one 32-col x 512B strip = 16KB; 16 gload_lds16 / block ----
    const int srow = c;
    const int skc  = q;
    auto stage = [&](uint8_t* dst, int st) {
        const uint8_t* base = wq + (size_t)(n0 + st * 32) * D_DIM;
        #pragma unroll
        for (int t = 0; t < 4; ++t) {
            const int p  = w * 4 + t;          // 0..15
            const int cb = p >> 3;             // 0..1 : 16-col group
            const int h  = p & 7;              // 0..7 : kc block of 4
            gload_lds16(base + (size_t)(cb * 16 + srow) * D_DIM + (h * 4 + skc) * 16,
                        dst + cb * 8192 + h * 1024);
        }
    };

    f32x4 rs0 = (f32x4){0.f, 0.f, 0.f, 0.f};
    f32x4 rs1 = (f32x4){0.f, 0.f, 0.f, 0.f};

    // per strip: 2 col-groups x 4 kt: bf (2 x ds_read_b128) feeds 2 MFMAs
    // (row-groups A,B); then exp2-accumulate into rs. No C-tile.
    auto compute = [&](const uint8_t* buf, int st, auto maskTag) {
        constexpr bool MASK = decltype(maskTag)::value;
        #pragma unroll
        for (int cb = 0; cb < 2; ++cb) {
            f32x4 a0 = (f32x4){0.f, 0.f, 0.f, 0.f};
            f32x4 a1 = (f32x4){0.f, 0.f, 0.f, 0.f};
            #pragma unroll
            for (int kt = 0; kt < 4; ++kt) {
                const uint8_t* p = buf + cb * 8192 + (kt * 8 + 2 * q) * 256 + c * 16;
                i32x4 lo = *(const i32x4*)p;
                i32x4 hi = *(const i32x4*)(p + 256);
                i32x8 bf = (i32x8){lo[0], lo[1], lo[2], lo[3],
                                   hi[0], hi[1], hi[2], hi[3]};
                a0 = __builtin_amdgcn_mfma_scale_f32_16x16x128_f8f6f4(
                        afA[kt], bf, a0, 0, 0, 0, 127, 0, 127);
                a1 = __builtin_amdgcn_mfma_scale_f32_16x16x128_f8f6f4(
                        afB[kt], bf, a1, 0, 0, 0, 127, 0, 127);
            }
            bool pad = false;
            if (MASK) pad = (n0 + st * 32 + cb * 16 + c) >= C_CLASSES;
            #pragma unroll
            for (int reg = 0; reg < 4; ++reg) {
                float t0 = __builtin_amdgcn_exp2f(fmaf(a0[reg], K_LOG2E_S, -K_LOG2E_S));
                float t1 = __builtin_amdgcn_exp2f(fmaf(a1[reg], K_LOG2E_S, -K_LOG2E_S));
                if (MASK && pad) { t0 = 0.f; t1 = 0.f; }
                rs0[reg] += t0;
                rs1[reg] += t1;
            }
        }
    };

    auto run = [&](auto maskTag) {
        stage(&Bs[0][0], 0);
        __syncthreads();                        // A frags + strip 0 resident
        #pragma unroll 1
        for (int st = 0; st < NSTRIP; st += 2) {
            stage(&Bs[1][0], st + 1);           // issue next BEFORE compute
            compute(&Bs[0][0], st, maskTag);
            __syncthreads();                    // drains stage -> Bs[1] ready
            if (st + 2 < NSTRIP) stage(&Bs[0][0], st + 2);
            compute(&Bs[1][0], st + 1, maskTag);
            __syncthreads();
        }
    };
    if (chunk == NCHUNK - 1) run(TrueT{}); else run(FalseT{});

    // wave-level col reduction: sum rs over the 16 col-lanes
    #pragma unroll
    for (int off = 1; off < 16; off <<= 1) {
        #pragma unroll
        for (int reg = 0; reg < 4; ++reg) {
            rs0[reg] += __shfl_xor(rs0[reg], off);
            rs1[reg] += __shfl_xor(rs1[reg], off);
        }
    }
    if (c == 0) {                               // lanes 0,16,32,48
        #pragma unroll
        for (int reg = 0; reg < 4; ++reg) {
            partials[(size_t)(r0 + q * 4 + reg) * NCHUNK + chunk]      = rs0[reg];
            partials[(size_t)(r0 + 16 + q * 4 + reg) * NCHUNK + chunk] = rs1[reg];
        }
    }
}

// -------- finalize: exact label logit + partial sum -> atomic mean NLL --------
// 2 waves per row: role 0 = exact label dot, role 1 = partials sum.
__global__ __launch_bounds__(256) void k_fin(const float* __restrict__ emb,
                                             const float* __restrict__ weight,
                                             const float* __restrict__ einv,
                                             const float* __restrict__ winv,
                                             const int* __restrict__ labels,
                                             const float* __restrict__ partials,
                                             float* __restrict__ out) {
    __shared__ float s_dot[2], s_ls[2];
    int widx = threadIdx.x >> 6;       // 0..3
    int lane = threadIdx.x & 63;
    int rloc = widx & 1;               // row within block
    int role = widx >> 1;              // 0 = dot, 1 = partials
    int b    = blockIdx.x * 2 + rloc;

    if (role == 0) {
        int label = labels[b];
        const float4* e  = (const float4*)(emb + (size_t)b * D_DIM);
        const float4* wt = (const float4*)(weight + (size_t)label * D_DIM);
        float4 e0 = e[lane],  e1 = e[lane + 64];
        float4 w0 = wt[lane], w1 = wt[lane + 64];
        float dot = e0.x*w0.x + e0.y*w0.y + e0.z*w0.z + e0.w*w0.w
                  + e1.x*w1.x + e1.y*w1.y + e1.z*w1.z + e1.w*w1.w;
        #pragma unroll
        for (int off = 32; off; off >>= 1) dot += __shfl_xor(dot, off);
        if (lane == 0) s_dot[rloc] = dot;
    } else {
        float p0 = partials[(size_t)b * NCHUNK + lane];
        float p1 = (lane + 64 < NCHUNK) ? partials[(size_t)b * NCHUNK + lane + 64] : 0.f;
        float ls = p0 + p1;
        #pragma unroll
        for (int off = 32; off; off >>= 1) ls += __shfl_xor(ls, off);
        if (lane == 0) s_ls[rloc] = ls;
    }
    __syncthreads();

    if (threadIdx.x < 2) {
        int r = threadIdx.x;
        int b2 = blockIdx.x * 2 + r;
        int label = labels[b2];
        float cosv   = s_dot[r] * einv[b2] * winv[label];
        float l_orig = ARC_SCALE * cosv;
        float l_adj  = ARC_SCALE * (cosv - ARC_MARGIN);
        // swap (fp8-accumulated) label term for exact margin-adjusted one
        float s_adj = s_ls[r] - __expf(l_orig - ARC_SCALE) + __expf(l_adj - ARC_SCALE);
        float v = ARC_SCALE + logf(s_adj) - l_adj;
        atomicAdd(out, v * (1.0f / (float)B_ROWS));
    }
}

extern "C" void kernel_launch(void* const* d_in, const int* in_sizes, int n_in,
                              void* d_out, int out_size, void* d_ws, size_t ws_size,
                              hipStream_t stream) {
    const float* emb    = (const float*)d_in[0];   // (2048, 512) f32
    const int*   labels = (const int*)d_in[1];     // (2048,)
    const float* weight = (const float*)d_in[2];   // (50000, 512) f32
    float* out = (float*)d_out;

    char* ws = (char*)d_ws;
    uint8_t* wq    = (uint8_t*)(ws + OFF_WQ);
    uint8_t* embq  = (uint8_t*)(ws + OFF_EMBQ);
    float* winv     = (float*)(ws + OFF_WINV);
    float* einv     = (float*)(ws + OFF_EINV);
    float* partials = (float*)(ws + OFF_PART);

    // (C_PAD + B_ROWS) rows, 4 rows/wave, 4 waves/block
    k_prep<<<(C_PAD + B_ROWS) / 16, 256, 0, stream>>>(emb, weight, embq, wq,
                                                      einv, winv, out);

    // 8 XCD x (14 chunks x 16 row-blocks) = 1792 blocks, no dead blocks
    k_gemm<<<1792, 256, 0, stream>>>(embq, wq, partials);

    k_fin<<<B_ROWS / 2, 256, 0, stream>>>(emb, weight, einv, winv, labels,
                                          partials, out);
}

// Round 5
// 234.151 us; speedup vs baseline: 1.8872x; 1.0286x over previous
//
#include <hip/hip_runtime.h>
#include <hip/hip_bf16.h>
#include <math.h>
#include <stdint.h>

// ArcFace loss via MX-fp8 (e4m3, identity scales) MFMA GEMM + fused
// fixed-max softmax. B=2048, D=512, C=50000. Output: scalar mean NLL (f32).
//
// R10: non-GEMM kernels attacked (k_gemm byte-identical to R9 as control;
//      R9 measured 76.6us / MfmaUtil 27% / no spill).
//  - k_fin: the 1024 same-address atomicAdds fully serialize at one L2 bank
//    (~60ns each ~= 60us). Replaced with 256 blocks x 8 rows -> per-block
//    partial written to ws, plus a 1-block k_sum reduction. ZERO atomics.
//  - k_prep: 8 rows/wave, all 16 float4 loads issued up-front (256 B/lane in
//    flight, 2x R9) -> raises the latency-bound BW ceiling 2x.
//
// Numerics: logits = 30*cos in [-30,30] -> fixed max 30, plain sums:
//   lse = 30 + log(sum_c exp(l_c - 30)); label logit recomputed exactly in
//   fp32 at finalize, so fp8 error only perturbs the softmax denominator.

#define B_ROWS    2048
#define D_DIM     512
#define C_CLASSES 50000
#define C_PAD     50176            // 112 * 448
#define NCHUNK    112              // 448-wide chunks
#define CH_COLS   448
#define NSTRIP    14               // 32-col strips per chunk
#define ARC_MARGIN 0.3f
#define ARC_SCALE  30.0f
#define ARC_EPS    1e-12f
#define K_LOG2E_S  43.2808512f     // 30 * log2(e)

// workspace layout (bytes)
#define OFF_WQ    0u               // 50176*512 = 25,690,112
#define OFF_EMBQ  25690112u        // 2048*512  =  1,048,576
#define OFF_WINV  26738688u        // 50000*4   =    200,000
#define OFF_EINV  26938688u        // 2048*4    =      8,192
#define OFF_PART  26946880u        // 2048*112*4 =   917,504
#define OFF_FINP  27864384u        // 256*4     =      1,024  -> total ~27.9 MB

typedef __attribute__((ext_vector_type(8))) int   i32x8;
typedef __attribute__((ext_vector_type(4))) int   i32x4;
typedef __attribute__((ext_vector_type(4))) float f32x4;

typedef __attribute__((address_space(1))) const unsigned int g_u32;
typedef __attribute__((address_space(3))) unsigned int       l_u32;

__device__ __forceinline__ void gload_lds16(const void* g, void* l) {
    // dest is wave-uniform LDS base; HW writes lane i at base + i*16
    g_u32* gp = (g_u32*)(uintptr_t)g;
    l_u32* lp = (l_u32*)(uintptr_t)l;
    __builtin_amdgcn_global_load_lds(gp, lp, 16, 0, 0);
}

// ---------------- prep: rows -> normalized e4m3 + inverse norms ----------------
// One wave per 8 consecutive rows; all 16 row-loads issued before any use
// (256 B/lane outstanding). Row space: [0,C_PAD) = weight (pad rows
// zero-filled), [C_PAD, C_PAD+B) = embeddings. All segments are multiples of
// 8 rows (50000, 176, 2048), so an 8-row group never straddles segments.
__global__ __launch_bounds__(256) void k_prep(const float* __restrict__ emb,
                                              const float* __restrict__ weight,
                                              uint8_t* __restrict__ embq,
                                              uint8_t* __restrict__ wq,
                                              float* __restrict__ einv,
                                              float* __restrict__ winv,
                                              float* __restrict__ out) {
    int wave = blockIdx.x * (blockDim.x >> 6) + (threadIdx.x >> 6);
    int lane = threadIdx.x & 63;
    int g0   = wave << 3;              // first of 8 consecutive rows

    const float* src;
    uint8_t* dst;
    float* invout;
    if (g0 >= C_PAD) {                 // embedding rows
        int row = g0 - C_PAD;
        src = emb + (size_t)row * D_DIM;
        dst = embq + (size_t)row * D_DIM;
        invout = einv + row;
    } else if (g0 >= C_CLASSES) {      // zero-fill pad classes
        int2 z = make_int2(0, 0);
        #pragma unroll
        for (int r = 0; r < 8; ++r)
            *(int2*)(wq + (size_t)(g0 + r) * D_DIM + lane * 8) = z;
        return;
    } else {                           // weight rows
        src = weight + (size_t)g0 * D_DIM;
        dst = wq + (size_t)g0 * D_DIM;
        invout = winv + g0;
    }

    // issue all 16 loads before any use: 256 B/lane outstanding
    const float4* r4 = (const float4*)src;
    float4 v[16];
    #pragma unroll
    for (int r = 0; r < 8; ++r) {
        v[2 * r]     = r4[r * 128 + lane * 2];
        v[2 * r + 1] = r4[r * 128 + lane * 2 + 1];
    }

    #pragma unroll
    for (int r = 0; r < 8; ++r) {
        float4 v0 = v[2 * r], v1 = v[2 * r + 1];
        float s = v0.x*v0.x + v0.y*v0.y + v0.z*v0.z + v0.w*v0.w
                + v1.x*v1.x + v1.y*v1.y + v1.z*v1.z + v1.w*v1.w;
        #pragma unroll
        for (int off = 32; off; off >>= 1) s += __shfl_xor(s, off);
        float rn = 1.0f / fmaxf(sqrtf(s), ARC_EPS);
        if (lane == 0) invout[r] = rn;
        int p0 = __builtin_amdgcn_cvt_pk_fp8_f32(v0.x * rn, v0.y * rn, 0, false);
        p0     = __builtin_amdgcn_cvt_pk_fp8_f32(v0.z * rn, v0.w * rn, p0, true);
        int p1 = __builtin_amdgcn_cvt_pk_fp8_f32(v1.x * rn, v1.y * rn, 0, false);
        p1     = __builtin_amdgcn_cvt_pk_fp8_f32(v1.z * rn, v1.w * rn, p1, true);
        *(int2*)(dst + (size_t)r * D_DIM + lane * 8) = make_int2(p0, p1);
    }
}

struct TrueT  { static constexpr bool value = true;  };
struct FalseT { static constexpr bool value = false; };

// ---------------- GEMM (MX-fp8, identity scales) + fused exp-sum -------------
// Block: 4 waves x 32 rows = 128 rows; chunk = 448 cols = 14 strips of 32.
// Wave's A rows (32 x 512B) live in regs (afA/afB, 64 VGPR). B strips staged
// in LDS (2 x 16KB dbuf), cell layout per 16-col group: [kc 0..31][col 0..15]
// 16B cells (gload_lds lane order == layout; frag ds_read_b128 conflict-free,
// same pattern as R5 which measured 0 bank conflicts). [UNCHANGED from R9]
__global__ __launch_bounds__(256) void k_gemm(const uint8_t* __restrict__ embq,
                                              const uint8_t* __restrict__ wq,
                                              float* __restrict__ partials) {
    __shared__ __align__(16) uint8_t Bs[2][16384];

    const int tid  = threadIdx.x;
    const int w    = tid >> 6;         // wave 0..3
    const int lane = tid & 63;
    const int c    = lane & 15;        // row/col within 16-group
    const int q    = lane >> 4;        // k-slice quad

    // XCD-affinity: consecutive ids round-robin XCDs; XCD x owns chunks
    // [x*14, x*14+14) for ALL row-blocks -> 3.2MB B slice stays in its L2.
    const int id  = blockIdx.x;        // 0..1791
    const int xcd = id & 7;
    const int s   = id >> 3;           // 0..223
    const int ci  = s % 14;
    const int rb  = s / 14;            // 0..15
    const int chunk = xcd * 14 + ci;
    const int b0 = rb * 128;
    const int n0 = chunk * CH_COLS;

    // ---- A fragments: wave's 32 rows, full K=512, in registers ----
    const int r0 = b0 + w * 32;
    i32x8 afA[4], afB[4];
    #pragma unroll
    for (int kt = 0; kt < 4; ++kt) {
        const uint8_t* pa = embq + (size_t)(r0 + c) * D_DIM + kt * 128 + q * 32;
        const uint8_t* pb = embq + (size_t)(r0 + 16 + c) * D_DIM + kt * 128 + q * 32;
        i32x4 alo = *(const i32x4*)pa;
        i32x4 ahi = *(const i32x4*)(pa + 16);
        i32x4 blo = *(const i32x4*)pb;
        i32x4 bhi = *(const i32x4*)(pb + 16);
        afA[kt] = (i32x8){alo[0], alo[1], alo[2], alo[3], ahi[0], ahi[1], ahi[2], ahi[3]};
        afB[kt] = (i32x8){blo[0], blo[1], blo[2], blo[3], bhi[0], bhi[1], bhi[2], bhi[3]};
    }

    // ---- staging: one 32-col x 512B strip = 16KB; 16 gload_lds16 / block ----
    const int srow = c;
    const int skc  = q;
    auto stage = [&](uint8_t* dst, int st) {
        const uint8_t* base = wq + (size_t)(n0 + st * 32) * D_DIM;
        #pragma unroll
        for (int t = 0; t < 4; ++t) {
            const int p  = w * 4 + t;          // 0..15
            const int cb = p >> 3;             // 0..1 : 16-col group
            const int h  = p & 7;              // 0..7 : kc block of 4
            gload_lds16(base + (size_t)(cb * 16 + srow) * D_DIM + (h * 4 + skc) * 16,
                        dst + cb * 8192 + h * 1024);
        }
    };

    f32x4 rs0 = (f32x4){0.f, 0.f, 0.f, 0.f};
    f32x4 rs1 = (f32x4){0.f, 0.f, 0.f, 0.f};

    // per strip: 2 col-groups x 4 kt: bf (2 x ds_read_b128) feeds 2 MFMAs
    // (row-groups A,B); then exp2-accumulate into rs. No C-tile.
    auto compute = [&](const uint8_t* buf, int st, auto maskTag) {
        constexpr bool MASK = decltype(maskTag)::value;
        #pragma unroll
        for (int cb = 0; cb < 2; ++cb) {
            f32x4 a0 = (f32x4){0.f, 0.f, 0.f, 0.f};
            f32x4 a1 = (f32x4){0.f, 0.f, 0.f, 0.f};
            #pragma unroll
            for (int kt = 0; kt < 4; ++kt) {
                const uint8_t* p = buf + cb * 8192 + (kt * 8 + 2 * q) * 256 + c * 16;
                i32x4 lo = *(const i32x4*)p;
                i32x4 hi = *(const i32x4*)(p + 256);
                i32x8 bf = (i32x8){lo[0], lo[1], lo[2], lo[3],
                                   hi[0], hi[1], hi[2], hi[3]};
                a0 = __builtin_amdgcn_mfma_scale_f32_16x16x128_f8f6f4(
                        afA[kt], bf, a0, 0, 0, 0, 127, 0, 127);
                a1 = __builtin_amdgcn_mfma_scale_f32_16x16x128_f8f6f4(
                        afB[kt], bf, a1, 0, 0, 0, 127, 0, 127);
            }
            bool pad = false;
            if (MASK) pad = (n0 + st * 32 + cb * 16 + c) >= C_CLASSES;
            #pragma unroll
            for (int reg = 0; reg < 4; ++reg) {
                float t0 = __builtin_amdgcn_exp2f(fmaf(a0[reg], K_LOG2E_S, -K_LOG2E_S));
                float t1 = __builtin_amdgcn_exp2f(fmaf(a1[reg], K_LOG2E_S, -K_LOG2E_S));
                if (MASK && pad) { t0 = 0.f; t1 = 0.f; }
                rs0[reg] += t0;
                rs1[reg] += t1;
            }
        }
    };

    auto run = [&](auto maskTag) {
        stage(&Bs[0][0], 0);
        __syncthreads();                        // A frags + strip 0 resident
        #pragma unroll 1
        for (int st = 0; st < NSTRIP; st += 2) {
            stage(&Bs[1][0], st + 1);           // issue next BEFORE compute
            compute(&Bs[0][0], st, maskTag);
            __syncthreads();                    // drains stage -> Bs[1] ready
            if (st + 2 < NSTRIP) stage(&Bs[0][0], st + 2);
            compute(&Bs[1][0], st + 1, maskTag);
            __syncthreads();
        }
    };
    if (chunk == NCHUNK - 1) run(TrueT{}); else run(FalseT{});

    // wave-level col reduction: sum rs over the 16 col-lanes
    #pragma unroll
    for (int off = 1; off < 16; off <<= 1) {
        #pragma unroll
        for (int reg = 0; reg < 4; ++reg) {
            rs0[reg] += __shfl_xor(rs0[reg], off);
            rs1[reg] += __shfl_xor(rs1[reg], off);
        }
    }
    if (c == 0) {                               // lanes 0,16,32,48
        #pragma unroll
        for (int reg = 0; reg < 4; ++reg) {
            partials[(size_t)(r0 + q * 4 + reg) * NCHUNK + chunk]      = rs0[reg];
            partials[(size_t)(r0 + 16 + q * 4 + reg) * NCHUNK + chunk] = rs1[reg];
        }
    }
}

// -------- finalize: exact label logit + partial sum -> per-block partial ------
// 256 blocks x 8 rows. Wave handles 2 rows (all loads for both rows issued
// up-front); per-row math identical to R9 (same reduce orders). Block sum ->
// finpart[blockIdx]; NO atomics (1024 same-address atomicAdds serialized).
__global__ __launch_bounds__(256) void k_fin(const float* __restrict__ emb,
                                             const float* __restrict__ weight,
                                             const float* __restrict__ einv,
                                             const float* __restrict__ winv,
                                             const int* __restrict__ labels,
                                             const float* __restrict__ partials,
                                             float* __restrict__ finpart) {
    __shared__ float sm[8];
    int w    = threadIdx.x >> 6;       // 0..3
    int lane = threadIdx.x & 63;
    int b0   = blockIdx.x * 8 + w * 2; // wave's two rows: b0, b0+1

    int lab[2] = {labels[b0], labels[b0 + 1]};
    float4 e0[2], e1[2], w0[2], w1[2];
    float p0[2], p1[2];
    #pragma unroll
    for (int r = 0; r < 2; ++r) {      // issue all loads for both rows
        const float4* e  = (const float4*)(emb + (size_t)(b0 + r) * D_DIM);
        const float4* wt = (const float4*)(weight + (size_t)lab[r] * D_DIM);
        e0[r] = e[lane];  e1[r] = e[lane + 64];
        w0[r] = wt[lane]; w1[r] = wt[lane + 64];
        p0[r] = partials[(size_t)(b0 + r) * NCHUNK + lane];
        p1[r] = (lane + 64 < NCHUNK)
              ? partials[(size_t)(b0 + r) * NCHUNK + lane + 64] : 0.f;
    }

    #pragma unroll
    for (int r = 0; r < 2; ++r) {
        float dot = e0[r].x*w0[r].x + e0[r].y*w0[r].y + e0[r].z*w0[r].z + e0[r].w*w0[r].w
                  + e1[r].x*w1[r].x + e1[r].y*w1[r].y + e1[r].z*w1[r].z + e1[r].w*w1[r].w;
        float ls = p0[r] + p1[r];
        #pragma unroll
        for (int off = 32; off; off >>= 1) {
            dot += __shfl_xor(dot, off);
            ls  += __shfl_xor(ls, off);
        }
        if (lane == 0) {
            int b = b0 + r;
            float cosv   = dot * einv[b] * winv[lab[r]];
            float l_orig = ARC_SCALE * cosv;
            float l_adj  = ARC_SCALE * (cosv - ARC_MARGIN);
            // swap (fp8-accumulated) label term for exact margin-adjusted one
            float s_adj = ls - __expf(l_orig - ARC_SCALE) + __expf(l_adj - ARC_SCALE);
            sm[w * 2 + r] = ARC_SCALE + logf(s_adj) - l_adj;
        }
    }
    __syncthreads();
    if (threadIdx.x == 0) {
        float t = 0.f;
        #pragma unroll
        for (int i = 0; i < 8; ++i) t += sm[i];
        finpart[blockIdx.x] = t;
    }
}

// -------- k_sum: 256 block partials -> mean NLL (single block, no atomics) ----
__global__ __launch_bounds__(256) void k_sum(const float* __restrict__ finpart,
                                             float* __restrict__ out) {
    __shared__ float sm[4];
    int w = threadIdx.x >> 6, lane = threadIdx.x & 63;
    float v = finpart[threadIdx.x];
    #pragma unroll
    for (int off = 32; off; off >>= 1) v += __shfl_xor(v, off);
    if (lane == 0) sm[w] = v;
    __syncthreads();
    if (threadIdx.x == 0)
        out[0] = (sm[0] + sm[1] + sm[2] + sm[3]) * (1.0f / (float)B_ROWS);
}

extern "C" void kernel_launch(void* const* d_in, const int* in_sizes, int n_in,
                              void* d_out, int out_size, void* d_ws, size_t ws_size,
                              hipStream_t stream) {
    const float* emb    = (const float*)d_in[0];   // (2048, 512) f32
    const int*   labels = (const int*)d_in[1];     // (2048,)
    const float* weight = (const float*)d_in[2];   // (50000, 512) f32
    float* out = (float*)d_out;

    char* ws = (char*)d_ws;
    uint8_t* wq    = (uint8_t*)(ws + OFF_WQ);
    uint8_t* embq  = (uint8_t*)(ws + OFF_EMBQ);
    float* winv     = (float*)(ws + OFF_WINV);
    float* einv     = (float*)(ws + OFF_EINV);
    float* partials = (float*)(ws + OFF_PART);
    float* finpart  = (float*)(ws + OFF_FINP);

    // (C_PAD + B_ROWS) rows, 8 rows/wave, 4 waves/block
    k_prep<<<(C_PAD + B_ROWS) / 32, 256, 0, stream>>>(emb, weight, embq, wq,
                                                      einv, winv, out);

    // 8 XCD x (14 chunks x 16 row-blocks) = 1792 blocks, no dead blocks
    k_gemm<<<1792, 256, 0, stream>>>(embq, wq, partials);

    k_fin<<<B_ROWS / 8, 256, 0, stream>>>(emb, weight, einv, winv, labels,
                                          partials, finpart);
    k_sum<<<1, 256, 0, stream>>>(finpart, out);
}